// Round 1
// baseline (50.836 us; speedup 1.0000x reference)
//
#include <hip/hip_runtime.h>
#include <math.h>

#define G      26
#define NA     5
#define NC     20
#define NB     128
#define NT     1024
#define GG     (G*G)            // 676
#define CELLS  (NB*NA*GG)       // 432640
#define CH     (NC+5)           // 25
#define IGNORE_THRESH 0.6f
#define OBJ_SCALE   5.0f
#define NOOBJ_SCALE 1.0f
#define CLS_SCALE   1.0f
#define COORD_SCALE 1.0f
#define STRIDE_F    32.0f

__device__ __constant__ float c_aw[NA] = {1.08f, 3.42f, 6.63f, 9.42f, 16.62f};
__device__ __constant__ float c_ah[NA] = {1.19f, 4.41f, 11.38f, 5.11f, 10.52f};

__device__ __forceinline__ float sigmoidf(float v) {
    return 1.0f / (1.0f + expf(-v));
}

// -------- Pass 1: per-target scatter --------
__global__ void k_targets(const float* __restrict__ tg,
                          int* __restrict__ cell_tgt,
                          unsigned char* __restrict__ supp) {
    int t = blockIdx.x * blockDim.x + threadIdx.x;
    if (t >= NT) return;
    float bf = tg[t * 6 + 0];
    float cx = tg[t * 6 + 2] * (float)G;
    float cy = tg[t * 6 + 3] * (float)G;
    float gw = tg[t * 6 + 4] * (float)G;
    float gh = tg[t * 6 + 5] * (float)G;
    int b  = (int)bf;
    int gi = (int)floorf(cx);
    int gj = (int)floorf(cy);

    float best = -1.0f;
    int bn = 0;
    float ious[NA];
    #pragma unroll
    for (int a = 0; a < NA; ++a) {
        float inter = fminf(c_aw[a], gw) * fminf(c_ah[a], gh);
        float uni   = c_aw[a] * c_ah[a] + 1e-16f + gw * gh - inter;
        float iou   = inter / uni;
        ious[a] = iou;
        if (iou > best) { best = iou; bn = a; }   // strict > : first max wins (jnp.argmax)
    }

    int cell0 = b * NA * GG + gj * G + gi;        // cell for anchor 0
    atomicMax(&cell_tgt[cell0 + bn * GG], t);     // last target index wins (np semantics)
    #pragma unroll
    for (int a = 0; a < NA; ++a)
        if (ious[a] > IGNORE_THRESH) supp[cell0 + a * GG] = 1;
}

// -------- Pass 2: main elementwise + loss partials --------
__launch_bounds__(256)
__global__ void k_main(const float* __restrict__ x,
                       const float* __restrict__ tg,
                       const int* __restrict__ cell_tgt,
                       const unsigned char* __restrict__ supp,
                       float* __restrict__ out,
                       float* __restrict__ acc) {
    __shared__ float stage[256 * CH];   // 25600 B
    __shared__ float red[4][9];

    int cell = blockIdx.x * 256 + threadIdx.x;
    int i = cell % G;
    int j = (cell / G) % G;
    int a = (cell / GG) % NA;
    int b = cell / (NA * GG);

    const float* xp = x + ((size_t)(b * (NA * CH) + a * CH) * GG + (size_t)(j * G + i));
    float v[CH];
    #pragma unroll
    for (int c = 0; c < CH; ++c) v[c] = xp[(size_t)c * GG];

    float px = sigmoidf(v[0]);
    float py = sigmoidf(v[1]);
    float pw = v[2];
    float ph = v[3];
    float pconf = sigmoidf(v[4]);
    float bx = px + (float)i;
    float by = py + (float)j;
    float bw = expf(pw) * c_aw[a];
    float bh = expf(ph) * c_ah[a];

    float pcls[NC];
    #pragma unroll
    for (int c = 0; c < NC; ++c) pcls[c] = sigmoidf(v[5 + c]);

    // stage output row (25 floats) in LDS for coalesced store
    float* s = &stage[threadIdx.x * CH];
    s[0] = bx * STRIDE_F;
    s[1] = by * STRIDE_F;
    s[2] = bw * STRIDE_F;
    s[3] = bh * STRIDE_F;
    s[4] = pconf;
    #pragma unroll
    for (int c = 0; c < NC; ++c) s[5 + c] = pcls[c];

    // loss partials: {sx, sy, sw, sh, s_conf_obj, s_conf_noobj, s_cls, n_obj, n_noobj}
    float p[9];
    #pragma unroll
    for (int q = 0; q < 9; ++q) p[q] = 0.0f;

    int t = cell_tgt[cell];
    if (t >= 0) {
        float cx = tg[t * 6 + 2] * (float)G;
        float cy = tg[t * 6 + 3] * (float)G;
        float gw = tg[t * 6 + 4] * (float)G;
        float gh = tg[t * 6 + 5] * (float)G;
        int label = (int)tg[t * 6 + 1];
        float tx = cx - floorf(cx);
        float ty = cy - floorf(cy);
        float tw = logf(gw / c_aw[a] + 1e-16f);
        float th = logf(gh / c_ah[a] + 1e-16f);

        // bbox IoU (xywh, +1 convention)
        float b1x1 = bx - bw * 0.5f, b1x2 = bx + bw * 0.5f;
        float b1y1 = by - bh * 0.5f, b1y2 = by + bh * 0.5f;
        float b2x1 = cx - gw * 0.5f, b2x2 = cx + gw * 0.5f;
        float b2y1 = cy - gh * 0.5f, b2y2 = cy + gh * 0.5f;
        float iw = fmaxf(fminf(b1x2, b2x2) - fmaxf(b1x1, b2x1) + 1.0f, 0.0f);
        float ih = fmaxf(fminf(b1y2, b2y2) - fmaxf(b1y1, b2y1) + 1.0f, 0.0f);
        float inter = iw * ih;
        float a1 = (b1x2 - b1x1 + 1.0f) * (b1y2 - b1y1 + 1.0f);
        float a2 = (b2x2 - b2x1 + 1.0f) * (b2y2 - b2y1 + 1.0f);
        float iou = inter / (a1 + a2 - inter + 1e-16f);

        p[0] = (px - tx) * (px - tx);
        p[1] = (py - ty) * (py - ty);
        p[2] = (pw - tw) * (pw - tw);
        p[3] = (ph - th) * (ph - th);
        p[4] = (pconf - iou) * (pconf - iou);
        float cls = 0.0f;
        #pragma unroll
        for (int c = 0; c < NC; ++c) {
            float pc = fminf(fmaxf(pcls[c], 1e-12f), 1.0f - 1e-12f);
            float tc = (c == label) ? 1.0f : 0.0f;
            cls -= tc * logf(pc) + (1.0f - tc) * logf(1.0f - pc);
        }
        p[6] = cls;
        p[7] = 1.0f;                       // n_obj
    } else if (!supp[cell]) {
        p[5] = pconf * pconf;              // tconf == 0 at noobj cells
        p[8] = 1.0f;                       // n_noobj
    }

    // wave (64-lane) shuffle reduce, then cross-wave via LDS
    #pragma unroll
    for (int o = 32; o > 0; o >>= 1) {
        #pragma unroll
        for (int q = 0; q < 9; ++q) p[q] += __shfl_down(p[q], o);
    }
    int lane = threadIdx.x & 63;
    int wid  = threadIdx.x >> 6;
    if (lane == 0) {
        #pragma unroll
        for (int q = 0; q < 9; ++q) red[wid][q] = p[q];
    }
    __syncthreads();
    if (threadIdx.x < 9) {
        float sum = red[0][threadIdx.x] + red[1][threadIdx.x]
                  + red[2][threadIdx.x] + red[3][threadIdx.x];
        atomicAdd(&acc[threadIdx.x], sum);
    }

    // coalesced copy-out: block covers 256*25 contiguous floats
    float* ob = out + (size_t)blockIdx.x * (256 * CH);
    #pragma unroll
    for (int k = 0; k < CH; ++k)
        ob[k * 256 + threadIdx.x] = stage[k * 256 + threadIdx.x];
}

// -------- Pass 3: finalize scalar loss --------
__global__ void k_final(const float* __restrict__ acc, float* __restrict__ loss_out) {
    float n_obj   = acc[7];
    float n_noobj = acc[8];
    float l = COORD_SCALE * (acc[0] + acc[1] + acc[2] + acc[3]) / n_obj
            + OBJ_SCALE * acc[4] / n_obj
            + NOOBJ_SCALE * acc[5] / n_noobj
            + CLS_SCALE * acc[6] / (n_obj * (float)NC);
    *loss_out = l;
}

extern "C" void kernel_launch(void* const* d_in, const int* in_sizes, int n_in,
                              void* d_out, int out_size, void* d_ws, size_t ws_size,
                              hipStream_t stream) {
    const float* x  = (const float*)d_in[0];
    const float* tg = (const float*)d_in[1];
    float* out = (float*)d_out;

    char* ws = (char*)d_ws;
    int* cell_tgt       = (int*)ws;                               // CELLS ints
    unsigned char* supp = (unsigned char*)(ws + (size_t)CELLS * 4); // CELLS bytes
    float* acc          = (float*)(ws + (size_t)CELLS * 5);       // 9 floats (aligned: CELLS*5 % 16 == 0)

    hipMemsetAsync(cell_tgt, 0xFF, (size_t)CELLS * sizeof(int), stream);  // -1
    hipMemsetAsync(supp, 0, (size_t)CELLS, stream);
    hipMemsetAsync(acc, 0, 16 * sizeof(float), stream);

    k_targets<<<(NT + 255) / 256, 256, 0, stream>>>(tg, cell_tgt, supp);
    k_main<<<CELLS / 256, 256, 0, stream>>>(x, tg, cell_tgt, supp, out, acc);
    k_final<<<1, 1, 0, stream>>>(acc, out + (size_t)CELLS * CH);
}